// Round 1
// baseline (883.817 us; speedup 1.0000x reference)
//
#include <hip/hip_runtime.h>

#define NN 50000
#define NE 400000
#define IND 64
#define HID 128
#define H3 384
#define FDIM 960
#define NSEL 4096
#define EPSF 0.3f
#define SLOPEF 0.3f

__device__ __forceinline__ float leaky1(float v){ return v>=0.f? v : SLOPEF*v; }

// ---------- degree / CSR construction ----------
__global__ void k_deg(const int* __restrict__ d0, const int* __restrict__ d1,
                      const int* __restrict__ d2, int* __restrict__ deg){
  int t = blockIdx.x*256 + threadIdx.x;
  if (t >= 3*NE) return;
  int r = t / NE, e = t - r*NE;
  const int* D = (r==0)?d0:((r==1)?d1:d2);
  atomicAdd(&deg[r*NN + D[e]], 1);
}

__global__ void k_dnorm(const int* __restrict__ deg, float* __restrict__ dn){
  int t = blockIdx.x*256 + threadIdx.x;
  if (t >= 3*NN) return;
  int g = deg[t];
  dn[t] = (g>0) ? rsqrtf((float)g) : 0.f;
}

// one block per relation; chunked block-wide exclusive scan of degrees -> offsets
__global__ __launch_bounds__(1024) void k_scan(const int* __restrict__ deg, int* __restrict__ off){
  int r = blockIdx.x;
  const int* dg = deg + r*NN;
  int* o = off + r*(NN+1);
  __shared__ int wsum[16];
  __shared__ int carry;
  int lane = threadIdx.x & 63, wid = threadIdx.x >> 6;
  if (threadIdx.x==0){ o[0]=0; carry=0; }
  __syncthreads();
  for (int base=0; base<NN; base+=1024){
    int i = base + threadIdx.x;
    int v = (i<NN) ? dg[i] : 0;
    int x = v;
    #pragma unroll
    for (int s=1;s<64;s<<=1){ int y=__shfl_up(x,(unsigned)s); if(lane>=s) x+=y; }
    if (lane==63) wsum[wid]=x;
    __syncthreads();
    if (wid==0){
      int s16 = (lane<16)? wsum[lane] : 0;
      #pragma unroll
      for (int s=1;s<16;s<<=1){ int y=__shfl_up(s16,(unsigned)s); if(lane>=s) s16+=y; }
      if (lane<16) wsum[lane]=s16;
    }
    __syncthreads();
    int incl = carry + ((wid>0)? wsum[wid-1] : 0) + x;
    if (i<NN) o[i+1]=incl;
    __syncthreads();
    if (threadIdx.x==1023) carry = incl;
    __syncthreads();
  }
}

__global__ void k_fill(const int* __restrict__ s0,const int* __restrict__ d0,
                       const int* __restrict__ s1,const int* __restrict__ d1,
                       const int* __restrict__ s2,const int* __restrict__ d2,
                       const int* __restrict__ off, int* __restrict__ cur,
                       int* __restrict__ csrc, int* __restrict__ cdst){
  int t = blockIdx.x*256 + threadIdx.x;
  if (t >= 3*NE) return;
  int r = t/NE, e = t - r*NE;
  const int* S = (r==0)?s0:((r==1)?s1:s2);
  const int* D = (r==0)?d0:((r==1)?d1:d2);
  int dv = D[e], sv = S[e];
  int pos = off[r*(NN+1)+dv] + atomicAdd(&cur[r*NN+dv], 1);
  csrc[r*NE+pos] = sv;
  cdst[r*NE+pos] = dv;
}

// ---------- tiled f32 GEMM with leaky epilogue ----------
// WT: B stored [N,K] (nn.Linear weight); else [K,N]
template<int BM,int BN,int BK,int TM,int TN,bool WT,bool BIAS>
__global__ __launch_bounds__(256) void k_linear(
    const float* __restrict__ A, int lda, int M, int K,
    const float* __restrict__ B, int ldb,
    const float* __restrict__ bias,
    float* __restrict__ C, int ldc)
{
  constexpr int TX = BN/TN;
  constexpr int TY = BM/TM;
  static_assert(TX*TY==256, "256 threads");
  __shared__ float As[BK][BM+4];
  __shared__ float Bs[BK][BN+4];
  const int tid = threadIdx.x;
  const int tx = tid % TX, ty = tid / TX;
  const int bm = blockIdx.y*BM, bn = blockIdx.x*BN;
  float acc[TM][TN];
  #pragma unroll
  for (int i=0;i<TM;i++)
    #pragma unroll
    for (int j=0;j<TN;j++) acc[i][j]=0.f;

  for (int k0=0;k0<K;k0+=BK){
    #pragma unroll
    for (int idx=tid; idx<BM*BK; idx+=256){
      int m = idx/BK, kk = idx - m*BK;
      int row = bm+m; row = (row<M)? row : (M-1);
      As[kk][m] = A[(size_t)row*lda + k0+kk];
    }
    if (WT){
      #pragma unroll
      for (int idx=tid; idx<BN*BK; idx+=256){
        int nj = idx/BK, kk = idx - nj*BK;
        Bs[kk][nj] = B[(size_t)(bn+nj)*ldb + k0+kk];
      }
    } else {
      #pragma unroll
      for (int idx=tid; idx<BN*BK; idx+=256){
        int kk = idx/BN, nj = idx - kk*BN;
        Bs[kk][nj] = B[(size_t)(k0+kk)*ldb + bn+nj];
      }
    }
    __syncthreads();
    #pragma unroll
    for (int kk=0;kk<BK;kk++){
      float a[TM], b[TN];
      #pragma unroll
      for (int i=0;i<TM;i++) a[i]=As[kk][ty*TM+i];
      #pragma unroll
      for (int j=0;j<TN;j++) b[j]=Bs[kk][tx*TN+j];
      #pragma unroll
      for (int i=0;i<TM;i++)
        #pragma unroll
        for (int j=0;j<TN;j++) acc[i][j] = fmaf(a[i], b[j], acc[i][j]);
    }
    __syncthreads();
  }
  #pragma unroll
  for (int i=0;i<TM;i++){
    int row = bm+ty*TM+i;
    if (row<M){
      #pragma unroll
      for (int j=0;j<TN;j++){
        int col = bn+tx*TN+j;
        float v = acc[i][j];
        if (BIAS) v += bias[col];
        v = leaky1(v);
        C[(size_t)row*ldc+col] = v;
      }
    }
  }
}

// ---------- per-node gate scores (wave per node, 3 relations x {dst,src}) ----------
template<int D>
__global__ __launch_bounds__(256) void k_scores(const float* __restrict__ X,
    const float* __restrict__ g0, const float* __restrict__ g1, const float* __restrict__ g2,
    float* __restrict__ sd, float* __restrict__ ss){
  int w = (blockIdx.x*256 + threadIdx.x) >> 6;
  int lane = threadIdx.x & 63;
  if (w >= NN) return;
  const float* x = X + (size_t)w*D;
  float a0=0,a1=0,a2=0,a3=0,a4=0,a5=0;
  for (int k=lane; k<D; k+=64){
    float v = x[k];
    a0 = fmaf(v, g0[k],   a0);  a1 = fmaf(v, g0[D+k], a1);
    a2 = fmaf(v, g1[k],   a2);  a3 = fmaf(v, g1[D+k], a3);
    a4 = fmaf(v, g2[k],   a4);  a5 = fmaf(v, g2[D+k], a5);
  }
  #pragma unroll
  for (int s=32;s>0;s>>=1){
    a0 += __shfl_down(a0,(unsigned)s); a1 += __shfl_down(a1,(unsigned)s);
    a2 += __shfl_down(a2,(unsigned)s); a3 += __shfl_down(a3,(unsigned)s);
    a4 += __shfl_down(a4,(unsigned)s); a5 += __shfl_down(a5,(unsigned)s);
  }
  if (lane==0){
    sd[0*NN+w]=a0; ss[0*NN+w]=a1;
    sd[1*NN+w]=a2; ss[1*NN+w]=a3;
    sd[2*NN+w]=a4; ss[2*NN+w]=a5;
  }
}

// ---------- edge coefficients in CSR order ----------
__global__ void k_coeff(const int* __restrict__ csrc, const int* __restrict__ cdst,
    const float* __restrict__ sd, const float* __restrict__ ss,
    const float* __restrict__ dnv, const float* __restrict__ gbp,
    float* __restrict__ coeff){
  int p = blockIdx.x*256 + threadIdx.x;
  if (p >= NE) return;
  int s = csrc[p], dn = cdst[p];
  float a = tanhf(sd[dn] + ss[s] + gbp[0]);
  coeff[p] = a * dnv[dn] * dnv[s];
}

// ---------- aggregation: pre[n] = EPS*X[n] + sum_e coeff*X[src] ----------
template<int D>
__global__ __launch_bounds__(D) void k_gather(const float* __restrict__ X,
    const int* __restrict__ off, const int* __restrict__ csrc,
    const float* __restrict__ coeff, float* __restrict__ outp){
  int n = blockIdx.x;
  int k = threadIdx.x;
  float acc = EPSF * X[(size_t)n*D + k];
  int p0 = off[n], p1 = off[n+1];
  for (int p=p0; p<p1; p++){
    int s = csrc[p];
    float c = coeff[p];
    acc = fmaf(c, X[(size_t)s*D + k], acc);
  }
  outp[(size_t)n*D + k] = acc;
}

template<int D>
__global__ __launch_bounds__(D) void k_gather_sel(const float* __restrict__ X,
    const int* __restrict__ nodes,
    const int* __restrict__ off, const int* __restrict__ csrc,
    const float* __restrict__ coeff, float* __restrict__ outp){
  int i = blockIdx.x;
  int n = nodes[i];
  int k = threadIdx.x;
  float acc = EPSF * X[(size_t)n*D + k];
  int p0 = off[n], p1 = off[n+1];
  for (int p=p0; p<p1; p++){
    acc = fmaf(coeff[p], X[(size_t)csrc[p]*D + k], acc);
  }
  outp[(size_t)i*D + k] = acc;
}

// ---------- gather raw0/raw1/raw2 rows into nf ----------
__global__ __launch_bounds__(192) void k_nf_fill(const float* __restrict__ h,
    const float* __restrict__ raw1, const float* __restrict__ raw2,
    const int* __restrict__ nodes, float* __restrict__ nf){
  int i = blockIdx.x;
  int n = nodes[i];
  for (int c=threadIdx.x; c<576; c+=192){
    float v; int col;
    if (c < 64)       { v = h[(size_t)n*IND + c];            col = 384 + c; }
    else if (c < 192) { int q=c-64;  v = raw1[(size_t)n*HID + q]; col = 448 + q; }
    else              { int q=c-192; v = raw2[(size_t)n*H3  + q]; col = 576 + q; }
    nf[(size_t)i*FDIM + col] = v;
  }
}

// ---------- final tiny projection ----------
__global__ void k_final(const float* __restrict__ sbuf, const float* __restrict__ t3w,
                        const float* __restrict__ t3b, float* __restrict__ outp){
  int i = blockIdx.x*256 + threadIdx.x;
  if (i >= NSEL) return;
  const float* srow = sbuf + (size_t)i*64;
  float a0 = t3b[0], a1 = t3b[1];
  #pragma unroll
  for (int j=0;j<64;j++){
    float v = srow[j];
    a0 = fmaf(v, t3w[j],    a0);
    a1 = fmaf(v, t3w[64+j], a1);
  }
  outp[i*2+0] = a0;
  outp[i*2+1] = a1;
}

extern "C" void kernel_launch(void* const* d_in, const int* in_sizes, int n_in,
                              void* d_out, int out_size, void* d_ws, size_t ws_size,
                              hipStream_t stream){
  if (n_in < 32) return;
  const float* h = (const float*)d_in[0];
  const int* src[3] = {(const int*)d_in[1], (const int*)d_in[3], (const int*)d_in[5]};
  const int* dst[3] = {(const int*)d_in[2], (const int*)d_in[4], (const int*)d_in[6]};
  const int* nodes = (const int*)d_in[7];
  const float* t1w = (const float*)d_in[8];
  const float* t1b = (const float*)d_in[9];

  // input-order detection: dict order has gate2_1_w (768) at idx 12; signature order has gate1_2_w (256)
  bool dictOrder = (in_sizes[12] == 768);
  const float *g1w[3],*g1b[3],*g2w[3],*g2b[3],*hw1[3],*hw2[3];
  for (int r=0;r<3;r++){
    if (dictOrder){
      int base = 10 + r*6;
      g1w[r]=(const float*)d_in[base+0]; g1b[r]=(const float*)d_in[base+1];
      g2w[r]=(const float*)d_in[base+2]; g2b[r]=(const float*)d_in[base+3];
      hw1[r]=(const float*)d_in[base+4]; hw2[r]=(const float*)d_in[base+5];
    } else {
      g1w[r]=(const float*)d_in[10+2*r]; g1b[r]=(const float*)d_in[11+2*r];
      g2w[r]=(const float*)d_in[16+2*r]; g2b[r]=(const float*)d_in[17+2*r];
      hw1[r]=(const float*)d_in[22+r];   hw2[r]=(const float*)d_in[25+r];
    }
  }
  const float* t2w = (const float*)d_in[28];
  const float* t2b = (const float*)d_in[29];
  const float* t3w = (const float*)d_in[30];
  const float* t3b = (const float*)d_in[31];
  float* outp = (float*)d_out;

  // workspace carve (≈175 MB)
  char* w = (char*)d_ws;
  auto carve = [&](size_t elems)->void*{
    void* p = (void*)w;
    w += ((elems*4 + 255) & ~size_t(255));
    return p;
  };
  int*   deg  = (int*)  carve((size_t)6*NN);       // deg[3N] then cur[3N], one memset
  int*   cur  = deg + 3*NN;
  int*   off  = (int*)  carve((size_t)3*(NN+1));
  float* dnv  = (float*)carve((size_t)3*NN);
  int*   csrc = (int*)  carve((size_t)3*NE);
  int*   cdst = (int*)  carve((size_t)3*NE);
  float* sd1  = (float*)carve((size_t)3*NN);
  float* ss1  = (float*)carve((size_t)3*NN);
  float* sd2  = (float*)carve((size_t)3*NN);
  float* ss2  = (float*)carve((size_t)3*NN);
  float* coef = (float*)carve((size_t)NE);
  float* raw1 = (float*)carve((size_t)NN*HID);
  float* raw2 = (float*)carve((size_t)NN*H3);
  float* pre1 = (float*)carve((size_t)NN*HID);
  float* pre2 = (float*)carve((size_t)NSEL*H3);
  float* nf   = (float*)carve((size_t)NSEL*FDIM);
  float* sbuf = (float*)carve((size_t)NSEL*64);

  hipMemsetAsync(deg, 0, (size_t)6*NN*4, stream);
  k_deg  <<<(3*NE+255)/256, 256, 0, stream>>>(dst[0], dst[1], dst[2], deg);
  k_dnorm<<<(3*NN+255)/256, 256, 0, stream>>>(deg, dnv);
  k_scan <<<3, 1024, 0, stream>>>(deg, off);
  k_fill <<<(3*NE+255)/256, 256, 0, stream>>>(src[0],dst[0],src[1],dst[1],src[2],dst[2],
                                              off, cur, csrc, cdst);

  // raw1 = leaky(h @ t1_w^T + t1_b)
  k_linear<128,128,16,8,8,true,true><<<dim3(1,(NN+127)/128), 256, 0, stream>>>(
      h, IND, NN, IND, t1w, IND, t1b, raw1, HID);

  k_scores<HID><<<(NN+3)/4, 256, 0, stream>>>(raw1, g1w[0], g1w[1], g1w[2], sd1, ss1);

  for (int r=0;r<3;r++){
    k_coeff<<<(NE+255)/256, 256, 0, stream>>>(csrc+(size_t)r*NE, cdst+(size_t)r*NE,
                                              sd1+r*NN, ss1+r*NN, dnv+r*NN, g1b[r], coef);
    k_gather<HID><<<NN, HID, 0, stream>>>(raw1, off+r*(NN+1), csrc+(size_t)r*NE, coef, pre1);
    // raw2[:, r*128:(r+1)*128] = leaky(pre1 @ hw1_r)
    k_linear<128,128,16,8,8,false,false><<<dim3(1,(NN+127)/128), 256, 0, stream>>>(
        pre1, HID, NN, HID, hw1[r], HID, nullptr, raw2 + r*HID, H3);
  }

  k_scores<H3><<<(NN+3)/4, 256, 0, stream>>>(raw2, g2w[0], g2w[1], g2w[2], sd2, ss2);

  for (int r=0;r<3;r++){
    k_coeff<<<(NE+255)/256, 256, 0, stream>>>(csrc+(size_t)r*NE, cdst+(size_t)r*NE,
                                              sd2+r*NN, ss2+r*NN, dnv+r*NN, g2b[r], coef);
    k_gather_sel<H3><<<NSEL, H3, 0, stream>>>(raw2, nodes, off+r*(NN+1),
                                              csrc+(size_t)r*NE, coef, pre2);
    // nf[:, r*128:(r+1)*128] = leaky(pre2 @ hw2_r)
    k_linear<32,128,16,2,8,false,false><<<dim3(1,(NSEL+31)/32), 256, 0, stream>>>(
        pre2, H3, NSEL, H3, hw2[r], HID, nullptr, nf + r*HID, FDIM);
  }

  k_nf_fill<<<NSEL, 192, 0, stream>>>(h, raw1, raw2, nodes, nf);

  // s = leaky(nf @ t2_w^T + t2_b)
  k_linear<64,64,16,4,4,true,true><<<dim3(1,(NSEL+63)/64), 256, 0, stream>>>(
      nf, FDIM, NSEL, FDIM, t2w, FDIM, t2b, sbuf, 64);

  k_final<<<(NSEL+255)/256, 256, 0, stream>>>(sbuf, t3w, t3b, outp);
}

// Round 2
// 609.992 us; speedup vs baseline: 1.4489x; 1.4489x over previous
//
#include <hip/hip_runtime.h>

#define NN 50000
#define NE 400000
#define IND 64
#define HID 128
#define H3 384
#define FDIM 960
#define NSEL 4096
#define EPSF 0.3f
#define SLOPEF 0.3f
#define KSPLIT 5
#define KCH 192

__device__ __forceinline__ float leaky1(float v){ return v>=0.f? v : SLOPEF*v; }

// ---------- degree / CSR construction ----------
__global__ void k_deg(const int* __restrict__ d0, const int* __restrict__ d1,
                      const int* __restrict__ d2, int* __restrict__ deg){
  int t = blockIdx.x*256 + threadIdx.x;
  if (t >= 3*NE) return;
  int r = t / NE, e = t - r*NE;
  const int* D = (r==0)?d0:((r==1)?d1:d2);
  atomicAdd(&deg[r*NN + D[e]], 1);
}

__global__ void k_dnorm(const int* __restrict__ deg, float* __restrict__ dn){
  int t = blockIdx.x*256 + threadIdx.x;
  if (t >= 3*NN) return;
  int g = deg[t];
  dn[t] = (g>0) ? rsqrtf((float)g) : 0.f;
}

// one block per relation; chunked block-wide exclusive scan of degrees -> offsets
__global__ __launch_bounds__(1024) void k_scan(const int* __restrict__ deg, int* __restrict__ off){
  int r = blockIdx.x;
  const int* dg = deg + r*NN;
  int* o = off + r*(NN+1);
  __shared__ int wsum[16];
  __shared__ int carry;
  int lane = threadIdx.x & 63, wid = threadIdx.x >> 6;
  if (threadIdx.x==0){ o[0]=0; carry=0; }
  __syncthreads();
  for (int base=0; base<NN; base+=1024){
    int i = base + threadIdx.x;
    int v = (i<NN) ? dg[i] : 0;
    int x = v;
    #pragma unroll
    for (int s=1;s<64;s<<=1){ int y=__shfl_up(x,(unsigned)s); if(lane>=s) x+=y; }
    if (lane==63) wsum[wid]=x;
    __syncthreads();
    if (wid==0){
      int s16 = (lane<16)? wsum[lane] : 0;
      #pragma unroll
      for (int s=1;s<16;s<<=1){ int y=__shfl_up(s16,(unsigned)s); if(lane>=s) s16+=y; }
      if (lane<16) wsum[lane]=s16;
    }
    __syncthreads();
    int incl = carry + ((wid>0)? wsum[wid-1] : 0) + x;
    if (i<NN) o[i+1]=incl;
    __syncthreads();
    if (threadIdx.x==1023) carry = incl;
    __syncthreads();
  }
}

// counting-sort fill: only src stored (dst implied by CSR bucket)
__global__ void k_fill2(const int* __restrict__ s0,const int* __restrict__ d0,
                        const int* __restrict__ s1,const int* __restrict__ d1,
                        const int* __restrict__ s2,const int* __restrict__ d2,
                        const int* __restrict__ off, int* __restrict__ cur,
                        int* __restrict__ csrc){
  int t = blockIdx.x*256 + threadIdx.x;
  if (t >= 3*NE) return;
  int r = t/NE, e = t - r*NE;
  const int* S = (r==0)?s0:((r==1)?s1:s2);
  const int* D = (r==0)?d0:((r==1)?d1:d2);
  int dv = D[e], sv = S[e];
  int pos = off[r*(NN+1)+dv] + atomicAdd(&cur[r*NN+dv], 1);
  csrc[(size_t)r*NE+pos] = sv;
}

// ---------- tiled f32 GEMM with leaky epilogue ----------
template<int BM,int BN,int BK,int TM,int TN,bool WT,bool BIAS>
__global__ __launch_bounds__(256) void k_linear(
    const float* __restrict__ A, int lda, int M, int K,
    const float* __restrict__ B, int ldb,
    const float* __restrict__ bias,
    float* __restrict__ C, int ldc)
{
  constexpr int TX = BN/TN;
  constexpr int TY = BM/TM;
  static_assert(TX*TY==256, "256 threads");
  __shared__ float As[BK][BM+4];
  __shared__ float Bs[BK][BN+4];
  const int tid = threadIdx.x;
  const int tx = tid % TX, ty = tid / TX;
  const int bm = blockIdx.y*BM, bn = blockIdx.x*BN;
  float acc[TM][TN];
  #pragma unroll
  for (int i=0;i<TM;i++)
    #pragma unroll
    for (int j=0;j<TN;j++) acc[i][j]=0.f;

  for (int k0=0;k0<K;k0+=BK){
    #pragma unroll
    for (int idx=tid; idx<BM*BK; idx+=256){
      int m = idx/BK, kk = idx - m*BK;
      int row = bm+m; row = (row<M)? row : (M-1);
      As[kk][m] = A[(size_t)row*lda + k0+kk];
    }
    if (WT){
      #pragma unroll
      for (int idx=tid; idx<BN*BK; idx+=256){
        int nj = idx/BK, kk = idx - nj*BK;
        Bs[kk][nj] = B[(size_t)(bn+nj)*ldb + k0+kk];
      }
    } else {
      #pragma unroll
      for (int idx=tid; idx<BN*BK; idx+=256){
        int kk = idx/BN, nj = idx - kk*BN;
        Bs[kk][nj] = B[(size_t)(k0+kk)*ldb + bn+nj];
      }
    }
    __syncthreads();
    #pragma unroll
    for (int kk=0;kk<BK;kk++){
      float a[TM], b[TN];
      #pragma unroll
      for (int i=0;i<TM;i++) a[i]=As[kk][ty*TM+i];
      #pragma unroll
      for (int j=0;j<TN;j++) b[j]=Bs[kk][tx*TN+j];
      #pragma unroll
      for (int i=0;i<TM;i++)
        #pragma unroll
        for (int j=0;j<TN;j++) acc[i][j] = fmaf(a[i], b[j], acc[i][j]);
    }
    __syncthreads();
  }
  #pragma unroll
  for (int i=0;i<TM;i++){
    int row = bm+ty*TM+i;
    if (row<M){
      #pragma unroll
      for (int j=0;j<TN;j++){
        int col = bn+tx*TN+j;
        float v = acc[i][j];
        if (BIAS) v += bias[col];
        v = leaky1(v);
        C[(size_t)row*ldc+col] = v;
      }
    }
  }
}

// z-batched (3 relations) GEMM, B in [K,N] layout, leaky, no bias
template<int BM,int BN,int BK,int TM,int TN>
__global__ __launch_bounds__(256) void k_linear3(
    const float* __restrict__ A0, int lda, int M, int K, size_t strideA,
    const float* __restrict__ B0, const float* __restrict__ B1, const float* __restrict__ B2,
    int ldb, float* __restrict__ C, int ldc, int colStride)
{
  constexpr int TX = BN/TN;
  constexpr int TY = BM/TM;
  static_assert(TX*TY==256, "256 threads");
  __shared__ float As[BK][BM+4];
  __shared__ float Bs[BK][BN+4];
  const int z = blockIdx.z;
  const float* A = A0 + (size_t)z*strideA;
  const float* B = (z==0)?B0:((z==1)?B1:B2);
  float* Cz = C + (size_t)z*colStride;
  const int tid = threadIdx.x;
  const int tx = tid % TX, ty = tid / TX;
  const int bm = blockIdx.y*BM, bn = blockIdx.x*BN;
  float acc[TM][TN];
  #pragma unroll
  for (int i=0;i<TM;i++)
    #pragma unroll
    for (int j=0;j<TN;j++) acc[i][j]=0.f;

  for (int k0=0;k0<K;k0+=BK){
    #pragma unroll
    for (int idx=tid; idx<BM*BK; idx+=256){
      int m = idx/BK, kk = idx - m*BK;
      int row = bm+m; row = (row<M)? row : (M-1);
      As[kk][m] = A[(size_t)row*lda + k0+kk];
    }
    #pragma unroll
    for (int idx=tid; idx<BN*BK; idx+=256){
      int kk = idx/BN, nj = idx - kk*BN;
      Bs[kk][nj] = B[(size_t)(k0+kk)*ldb + bn+nj];
    }
    __syncthreads();
    #pragma unroll
    for (int kk=0;kk<BK;kk++){
      float a[TM], b[TN];
      #pragma unroll
      for (int i=0;i<TM;i++) a[i]=As[kk][ty*TM+i];
      #pragma unroll
      for (int j=0;j<TN;j++) b[j]=Bs[kk][tx*TN+j];
      #pragma unroll
      for (int i=0;i<TM;i++)
        #pragma unroll
        for (int j=0;j<TN;j++) acc[i][j] = fmaf(a[i], b[j], acc[i][j]);
    }
    __syncthreads();
  }
  #pragma unroll
  for (int i=0;i<TM;i++){
    int row = bm+ty*TM+i;
    if (row<M){
      #pragma unroll
      for (int j=0;j<TN;j++){
        int col = bn+tx*TN+j;
        Cz[(size_t)row*ldc+col] = leaky1(acc[i][j]);
      }
    }
  }
}

// split-K GEMM for t2 (WT layout), raw partials
template<int BM,int BN,int BK,int TM,int TN>
__global__ __launch_bounds__(256) void k_linear_sk(
    const float* __restrict__ A, int lda, int M,
    const float* __restrict__ B, int ldb,
    float* __restrict__ part)
{
  constexpr int TX = BN/TN;
  constexpr int TY = BM/TM;
  static_assert(TX*TY==256, "256 threads");
  __shared__ float As[BK][BM+4];
  __shared__ float Bs[BK][BN+4];
  const int s = blockIdx.x;
  const int tid = threadIdx.x;
  const int tx = tid % TX, ty = tid / TX;
  const int bm = blockIdx.y*BM;
  float acc[TM][TN];
  #pragma unroll
  for (int i=0;i<TM;i++)
    #pragma unroll
    for (int j=0;j<TN;j++) acc[i][j]=0.f;

  const int kbeg = s*KCH;
  for (int k0=kbeg; k0<kbeg+KCH; k0+=BK){
    #pragma unroll
    for (int idx=tid; idx<BM*BK; idx+=256){
      int m = idx/BK, kk = idx - m*BK;
      int row = bm+m; row = (row<M)? row : (M-1);
      As[kk][m] = A[(size_t)row*lda + k0+kk];
    }
    #pragma unroll
    for (int idx=tid; idx<BN*BK; idx+=256){
      int nj = idx/BK, kk = idx - nj*BK;
      Bs[kk][nj] = B[(size_t)nj*ldb + k0+kk];
    }
    __syncthreads();
    #pragma unroll
    for (int kk=0;kk<BK;kk++){
      float a[TM], b[TN];
      #pragma unroll
      for (int i=0;i<TM;i++) a[i]=As[kk][ty*TM+i];
      #pragma unroll
      for (int j=0;j<TN;j++) b[j]=Bs[kk][tx*TN+j];
      #pragma unroll
      for (int i=0;i<TM;i++)
        #pragma unroll
        for (int j=0;j<TN;j++) acc[i][j] = fmaf(a[i], b[j], acc[i][j]);
    }
    __syncthreads();
  }
  #pragma unroll
  for (int i=0;i<TM;i++){
    int row = bm+ty*TM+i;
    if (row<M){
      #pragma unroll
      for (int j=0;j<TN;j++){
        int col = tx*TN+j;
        part[((size_t)s*M + row)*BN + col] = acc[i][j];
      }
    }
  }
}

// partial-reduce + bias + leaky + t3 projection, one wave per selected row
__global__ __launch_bounds__(256) void k_final_wave(
    const float* __restrict__ part, const float* __restrict__ t2b,
    const float* __restrict__ t3w, const float* __restrict__ t3b,
    float* __restrict__ outp)
{
  int w = (blockIdx.x*256 + threadIdx.x) >> 6;
  int j = threadIdx.x & 63;
  if (w >= NSEL) return;
  float v = 0.f;
  #pragma unroll
  for (int s=0;s<KSPLIT;s++) v += part[((size_t)s*NSEL + w)*64 + j];
  v += t2b[j];
  v = leaky1(v);
  float a0 = v*t3w[j], a1 = v*t3w[64+j];
  #pragma unroll
  for (int sft=32;sft>0;sft>>=1){
    a0 += __shfl_down(a0,(unsigned)sft);
    a1 += __shfl_down(a1,(unsigned)sft);
  }
  if (j==0){
    outp[2*w+0] = a0 + t3b[0];
    outp[2*w+1] = a1 + t3b[1];
  }
}

// ---------- per-node gate scores (wave per node, 3 relations x {dst,src}) ----------
template<int D>
__global__ __launch_bounds__(256) void k_scores(const float* __restrict__ X,
    const float* __restrict__ g0, const float* __restrict__ g1, const float* __restrict__ g2,
    float* __restrict__ sd, float* __restrict__ ss){
  int w = (blockIdx.x*256 + threadIdx.x) >> 6;
  int lane = threadIdx.x & 63;
  if (w >= NN) return;
  const float* x = X + (size_t)w*D;
  float a0=0,a1=0,a2=0,a3=0,a4=0,a5=0;
  for (int k=lane; k<D; k+=64){
    float v = x[k];
    a0 = fmaf(v, g0[k],   a0);  a1 = fmaf(v, g0[D+k], a1);
    a2 = fmaf(v, g1[k],   a2);  a3 = fmaf(v, g1[D+k], a3);
    a4 = fmaf(v, g2[k],   a4);  a5 = fmaf(v, g2[D+k], a5);
  }
  #pragma unroll
  for (int s=32;s>0;s>>=1){
    a0 += __shfl_down(a0,(unsigned)s); a1 += __shfl_down(a1,(unsigned)s);
    a2 += __shfl_down(a2,(unsigned)s); a3 += __shfl_down(a3,(unsigned)s);
    a4 += __shfl_down(a4,(unsigned)s); a5 += __shfl_down(a5,(unsigned)s);
  }
  if (lane==0){
    sd[0*NN+w]=a0; ss[0*NN+w]=a1;
    sd[1*NN+w]=a2; ss[1*NN+w]=a3;
    sd[2*NN+w]=a4; ss[2*NN+w]=a5;
  }
}

// ---------- aggregation with fused edge coefficients ----------
// pre[n] = EPS*X[n] + sum_p tanh(sd[n]+ss[s]+gb)*d[n]*d[s] * X[s]
template<int D,int CH>
__global__ __launch_bounds__(D) void k_gather_f(const float* __restrict__ X,
    const int* __restrict__ off, const int* __restrict__ csrc,
    const float* __restrict__ sd, const float* __restrict__ ss,
    const float* __restrict__ dnv, const float* __restrict__ gb,
    float* __restrict__ outp){
  __shared__ float sc[CH];
  __shared__ int ssrc[CH];
  int n = blockIdx.x;
  int k = threadIdx.x;
  float sd_n = sd[n], dn_n = dnv[n], gbv = gb[0];
  float acc = EPSF * X[(size_t)n*D + k];
  int p0 = off[n], p1 = off[n+1];
  for (int pc=p0; pc<p1; pc+=CH){
    int m = min(CH, p1-pc);
    if (k < m){
      int s = csrc[pc+k];
      ssrc[k] = s;
      sc[k] = tanhf(sd_n + ss[s] + gbv) * dn_n * dnv[s];
    }
    __syncthreads();
    for (int j=0;j<m;j++){
      acc = fmaf(sc[j], X[(size_t)ssrc[j]*D + k], acc);
    }
    __syncthreads();
  }
  outp[(size_t)n*D + k] = acc;
}

// layer-2: batched over 3 relations (blockIdx.y), only selected destinations
template<int D,int CH>
__global__ __launch_bounds__(D) void k_gather_sel3(const float* __restrict__ X,
    const int* __restrict__ nodes,
    const int* __restrict__ off, const int* __restrict__ csrc,
    const float* __restrict__ sd, const float* __restrict__ ss,
    const float* __restrict__ dnv,
    const float* __restrict__ gb0, const float* __restrict__ gb1, const float* __restrict__ gb2,
    float* __restrict__ outp){
  __shared__ float sc[CH];
  __shared__ int ssrc[CH];
  int r = blockIdx.y;
  int i = blockIdx.x;
  int n = nodes[i];
  int k = threadIdx.x;
  const int* offr = off + r*(NN+1);
  const int* csr  = csrc + (size_t)r*NE;
  const float* sdr = sd + r*NN;
  const float* ssr = ss + r*NN;
  const float* dnr = dnv + r*NN;
  float gbv = ((r==0)?gb0:((r==1)?gb1:gb2))[0];
  float sd_n = sdr[n], dn_n = dnr[n];
  float acc = EPSF * X[(size_t)n*D + k];
  int p0 = offr[n], p1 = offr[n+1];
  for (int pc=p0; pc<p1; pc+=CH){
    int m = min(CH, p1-pc);
    if (k < m){
      int s = csr[pc+k];
      ssrc[k] = s;
      sc[k] = tanhf(sd_n + ssr[s] + gbv) * dn_n * dnr[s];
    }
    __syncthreads();
    for (int j=0;j<m;j++){
      acc = fmaf(sc[j], X[(size_t)ssrc[j]*D + k], acc);
    }
    __syncthreads();
  }
  outp[((size_t)r*NSEL + i)*D + k] = acc;
}

// ---------- gather raw0/raw1/raw2 rows into nf ----------
__global__ __launch_bounds__(192) void k_nf_fill(const float* __restrict__ h,
    const float* __restrict__ raw1, const float* __restrict__ raw2,
    const int* __restrict__ nodes, float* __restrict__ nf){
  int i = blockIdx.x;
  int n = nodes[i];
  for (int c=threadIdx.x; c<576; c+=192){
    float v; int col;
    if (c < 64)       { v = h[(size_t)n*IND + c];            col = 384 + c; }
    else if (c < 192) { int q=c-64;  v = raw1[(size_t)n*HID + q]; col = 448 + q; }
    else              { int q=c-192; v = raw2[(size_t)n*H3  + q]; col = 576 + q; }
    nf[(size_t)i*FDIM + col] = v;
  }
}

extern "C" void kernel_launch(void* const* d_in, const int* in_sizes, int n_in,
                              void* d_out, int out_size, void* d_ws, size_t ws_size,
                              hipStream_t stream){
  if (n_in < 32) return;
  const float* h = (const float*)d_in[0];
  const int* src[3] = {(const int*)d_in[1], (const int*)d_in[3], (const int*)d_in[5]};
  const int* dst[3] = {(const int*)d_in[2], (const int*)d_in[4], (const int*)d_in[6]};
  const int* nodes = (const int*)d_in[7];
  const float* t1w = (const float*)d_in[8];
  const float* t1b = (const float*)d_in[9];

  bool dictOrder = (in_sizes[12] == 768);
  const float *g1w[3],*g1b[3],*g2w[3],*g2b[3],*hw1[3],*hw2[3];
  for (int r=0;r<3;r++){
    if (dictOrder){
      int base = 10 + r*6;
      g1w[r]=(const float*)d_in[base+0]; g1b[r]=(const float*)d_in[base+1];
      g2w[r]=(const float*)d_in[base+2]; g2b[r]=(const float*)d_in[base+3];
      hw1[r]=(const float*)d_in[base+4]; hw2[r]=(const float*)d_in[base+5];
    } else {
      g1w[r]=(const float*)d_in[10+2*r]; g1b[r]=(const float*)d_in[11+2*r];
      g2w[r]=(const float*)d_in[16+2*r]; g2b[r]=(const float*)d_in[17+2*r];
      hw1[r]=(const float*)d_in[22+r];   hw2[r]=(const float*)d_in[25+r];
    }
  }
  const float* t2w = (const float*)d_in[28];
  const float* t2b = (const float*)d_in[29];
  const float* t3w = (const float*)d_in[30];
  const float* t3b = (const float*)d_in[31];
  float* outp = (float*)d_out;

  // workspace carve (~154 MB)
  char* w = (char*)d_ws;
  auto carve = [&](size_t elems)->void*{
    void* p = (void*)w;
    w += ((elems*4 + 255) & ~size_t(255));
    return p;
  };
  int*   deg  = (int*)  carve((size_t)6*NN);       // deg[3N] + cur[3N], one memset
  int*   cur  = deg + 3*NN;
  int*   off  = (int*)  carve((size_t)3*(NN+1));
  float* dnv  = (float*)carve((size_t)3*NN);
  int*   csrc = (int*)  carve((size_t)3*NE);
  float* sd1  = (float*)carve((size_t)3*NN);
  float* ss1  = (float*)carve((size_t)3*NN);
  float* sd2  = (float*)carve((size_t)3*NN);
  float* ss2  = (float*)carve((size_t)3*NN);
  float* raw1 = (float*)carve((size_t)NN*HID);
  float* raw2 = (float*)carve((size_t)NN*H3);
  // union region: pre1 [NN*HID]  |  pre2 [3*NSEL*H3] + part [KSPLIT*NSEL*64]
  float* ureg = (float*)carve((size_t)NN*HID);
  float* pre1 = ureg;
  float* pre2 = ureg;
  float* part = ureg + (size_t)3*NSEL*H3;
  float* nf   = (float*)carve((size_t)NSEL*FDIM);

  hipMemsetAsync(deg, 0, (size_t)6*NN*4, stream);
  k_deg  <<<(3*NE+255)/256, 256, 0, stream>>>(dst[0], dst[1], dst[2], deg);
  k_dnorm<<<(3*NN+255)/256, 256, 0, stream>>>(deg, dnv);
  k_scan <<<3, 1024, 0, stream>>>(deg, off);
  k_fill2<<<(3*NE+255)/256, 256, 0, stream>>>(src[0],dst[0],src[1],dst[1],src[2],dst[2],
                                              off, cur, csrc);

  // raw1 = leaky(h @ t1_w^T + t1_b)
  k_linear<128,128,16,8,8,true,true><<<dim3(1,(NN+127)/128), 256, 0, stream>>>(
      h, IND, NN, IND, t1w, IND, t1b, raw1, HID);

  k_scores<HID><<<(NN+3)/4, 256, 0, stream>>>(raw1, g1w[0], g1w[1], g1w[2], sd1, ss1);

  for (int r=0;r<3;r++){
    k_gather_f<HID,128><<<NN, HID, 0, stream>>>(raw1, off+r*(NN+1), csrc+(size_t)r*NE,
                                                sd1+r*NN, ss1+r*NN, dnv+r*NN, g1b[r], pre1);
    k_linear<128,128,16,8,8,false,false><<<dim3(1,(NN+127)/128), 256, 0, stream>>>(
        pre1, HID, NN, HID, hw1[r], HID, nullptr, raw2 + r*HID, H3);
  }

  k_scores<H3><<<(NN+3)/4, 256, 0, stream>>>(raw2, g2w[0], g2w[1], g2w[2], sd2, ss2);

  // batched selected gather over 3 relations
  k_gather_sel3<H3,128><<<dim3(NSEL,3), H3, 0, stream>>>(raw2, nodes, off, csrc,
      sd2, ss2, dnv, g2b[0], g2b[1], g2b[2], pre2);

  // batched hw2 GEMMs: nf[:, r*128:(r+1)*128] = leaky(pre2_r @ hw2_r)
  k_linear3<32,128,16,2,8><<<dim3(1,(NSEL+31)/32,3), 256, 0, stream>>>(
      pre2, H3, NSEL, H3, (size_t)NSEL*H3, hw2[0], hw2[1], hw2[2], HID, nf, FDIM, HID);

  k_nf_fill<<<NSEL, 192, 0, stream>>>(h, raw1, raw2, nodes, nf);

  // t2 split-K partials then fused reduce + leaky + t3
  k_linear_sk<64,64,16,4,4><<<dim3(KSPLIT,(NSEL+63)/64), 256, 0, stream>>>(
      nf, FDIM, NSEL, t2w, FDIM, part);
  k_final_wave<<<(NSEL*64+255)/256, 256, 0, stream>>>(part, t2b, t3w, t3b, outp);
}

// Round 3
// 521.751 us; speedup vs baseline: 1.6939x; 1.1691x over previous
//
#include <hip/hip_runtime.h>

#define NN 50000
#define NE 400000
#define IND 64
#define HID 128
#define H3 384
#define FDIM 960
#define NSEL 4096
#define EPSF 0.3f
#define SLOPEF 0.3f
#define SCHUNK 2048
#define NCHUNK 25          // ceil(NN/SCHUNK)
#define KS2 10             // t2 split-K
#define KCH2 96            // 960/10
#define KS3 3              // hw2 split-K
#define KCH3 128           // 384/3

__device__ __forceinline__ float leaky1(float v){ return v>=0.f? v : SLOPEF*v; }

// ---------- degree ----------
__global__ void k_deg(const int* __restrict__ d0, const int* __restrict__ d1,
                      const int* __restrict__ d2, int* __restrict__ deg){
  int t = blockIdx.x*256 + threadIdx.x;
  if (t >= 3*NE) return;
  int r = t / NE, e = t - r*NE;
  const int* D = (r==0)?d0:((r==1)?d1:d2);
  atomicAdd(&deg[r*NN + D[e]], 1);
}

// ---------- 3-phase parallel scan (75 blocks), fused dnorm ----------
__global__ __launch_bounds__(256) void k_scan_a(const int* __restrict__ deg,
    int* __restrict__ off, int* __restrict__ bsum, float* __restrict__ dnv){
  int b = blockIdx.x;
  int r = b / NCHUNK, c = b - r*NCHUNK;
  const int* dg = deg + r*NN;
  int* o = off + r*(NN+1);
  int t = threadIdx.x;
  int base = c*SCHUNK + t*8;
  int v[8];
  #pragma unroll
  for (int j=0;j<8;j++){
    int i = base+j;
    int g = (i<NN)? dg[i] : 0;
    v[j] = g;
    if (i<NN) dnv[r*NN+i] = (g>0)? rsqrtf((float)g) : 0.f;
  }
  int s=0;
  #pragma unroll
  for (int j=0;j<8;j++){ s += v[j]; v[j] = s; }   // local inclusive
  int lane = t & 63, wid = t >> 6;
  int x = s;
  #pragma unroll
  for (int d=1; d<64; d<<=1){ int y=__shfl_up(x,(unsigned)d); if(lane>=d) x+=y; }
  __shared__ int ws[4];
  if (lane==63) ws[wid]=x;
  __syncthreads();
  int wpre = 0;
  if (wid>0) wpre += ws[0];
  if (wid>1) wpre += ws[1];
  if (wid>2) wpre += ws[2];
  int excl = wpre + x - s;
  #pragma unroll
  for (int j=0;j<8;j++){ int i=base+j; if (i<NN) o[i+1] = excl + v[j]; }
  if (t==255) bsum[b] = wpre + x;
}

__global__ void k_scan_b(int* __restrict__ bsum){
  int r = threadIdx.x;
  if (r < 3){
    int run = 0;
    for (int c=0;c<NCHUNK;c++){
      int t = bsum[r*NCHUNK+c];
      bsum[r*NCHUNK+c] = run;
      run += t;
    }
  }
}

__global__ __launch_bounds__(256) void k_scan_c(int* __restrict__ off,
                                                const int* __restrict__ bsum){
  int b = blockIdx.x;
  int r = b / NCHUNK, c = b - r*NCHUNK;
  int add = bsum[b];
  int* o = off + r*(NN+1);
  if (threadIdx.x==0 && c==0) o[0]=0;
  int base = c*SCHUNK;
  for (int j=threadIdx.x; j<SCHUNK; j+=256){
    int i = base+j;
    if (i<NN) o[i+1] += add;
  }
}

// counting-sort fill: only src stored
__global__ void k_fill2(const int* __restrict__ s0,const int* __restrict__ d0,
                        const int* __restrict__ s1,const int* __restrict__ d1,
                        const int* __restrict__ s2,const int* __restrict__ d2,
                        const int* __restrict__ off, int* __restrict__ cur,
                        int* __restrict__ csrc){
  int t = blockIdx.x*256 + threadIdx.x;
  if (t >= 3*NE) return;
  int r = t/NE, e = t - r*NE;
  const int* S = (r==0)?s0:((r==1)?s1:s2);
  const int* D = (r==0)?d0:((r==1)?d1:d2);
  int dv = D[e], sv = S[e];
  int pos = off[r*(NN+1)+dv] + atomicAdd(&cur[r*NN+dv], 1);
  csrc[(size_t)r*NE+pos] = sv;
}

// ---------- vectorized tiled f32 GEMM with leaky epilogue ----------
template<int BM,int BN,int BK,int TM,int TN,bool WT,bool BIAS>
__global__ __launch_bounds__(256) void k_gemm(
    const float* __restrict__ A, int lda, int M, int K,
    const float* __restrict__ B, int ldb,
    const float* __restrict__ bias,
    float* __restrict__ C, int ldc)
{
  constexpr int TX = BN/TN;
  constexpr int TY = BM/TM;
  static_assert(TX*TY==256, "256 threads");
  static_assert(BK%4==0 && BN%4==0 && TN%4==0, "vec4");
  __shared__ float As[BK][BM+4];
  __shared__ float Bs[BK][BN+4];
  const int tid = threadIdx.x;
  const int tx = tid % TX, ty = tid / TX;
  const int bm = blockIdx.y*BM, bn = blockIdx.x*BN;
  float acc[TM][TN];
  #pragma unroll
  for (int i=0;i<TM;i++)
    #pragma unroll
    for (int j=0;j<TN;j++) acc[i][j]=0.f;

  for (int k0=0;k0<K;k0+=BK){
    #pragma unroll
    for (int q=tid; q<BM*BK/4; q+=256){
      int m = q/(BK/4), kq = q - m*(BK/4);
      int row = bm+m; row = (row<M)? row : (M-1);
      const float4 v = *(const float4*)&A[(size_t)row*lda + k0 + kq*4];
      As[kq*4+0][m]=v.x; As[kq*4+1][m]=v.y; As[kq*4+2][m]=v.z; As[kq*4+3][m]=v.w;
    }
    if (WT){
      #pragma unroll
      for (int q=tid; q<BN*BK/4; q+=256){
        int nj = q/(BK/4), kq = q - nj*(BK/4);
        const float4 v = *(const float4*)&B[(size_t)(bn+nj)*ldb + k0 + kq*4];
        Bs[kq*4+0][nj]=v.x; Bs[kq*4+1][nj]=v.y; Bs[kq*4+2][nj]=v.z; Bs[kq*4+3][nj]=v.w;
      }
    } else {
      #pragma unroll
      for (int q=tid; q<BN*BK/4; q+=256){
        int kk = q/(BN/4), nq = q - kk*(BN/4);
        const float4 v = *(const float4*)&B[(size_t)(k0+kk)*ldb + bn + nq*4];
        *(float4*)&Bs[kk][nq*4] = v;
      }
    }
    __syncthreads();
    #pragma unroll
    for (int kk=0;kk<BK;kk++){
      float a[TM], b[TN];
      #pragma unroll
      for (int i=0;i<TM;i++) a[i]=As[kk][ty*TM+i];
      #pragma unroll
      for (int j=0;j<TN;j++) b[j]=Bs[kk][tx*TN+j];
      #pragma unroll
      for (int i=0;i<TM;i++)
        #pragma unroll
        for (int j=0;j<TN;j++) acc[i][j] = fmaf(a[i], b[j], acc[i][j]);
    }
    __syncthreads();
  }
  #pragma unroll
  for (int i=0;i<TM;i++){
    int row = bm+ty*TM+i;
    if (row<M){
      #pragma unroll
      for (int j4=0;j4<TN/4;j4++){
        float o[4];
        #pragma unroll
        for (int u=0;u<4;u++){
          int j = j4*4+u;
          float v = acc[i][j];
          if (BIAS) v += bias[bn+tx*TN+j];
          o[u] = leaky1(v);
        }
        *(float4*)&C[(size_t)row*ldc + bn + tx*TN + j4*4] = make_float4(o[0],o[1],o[2],o[3]);
      }
    }
  }
}

// ---------- split-K (optionally z-batched) GEMM, raw partials ----------
// blockIdx: x = ksplit, y = m-tile, z = relation
template<int BM,int BN,int BK,int TM,int TN,bool WT,int NKS>
__global__ __launch_bounds__(256) void k_sk(
    const float* __restrict__ A0, int lda, int M, int kch, size_t strideA,
    const float* __restrict__ B0, const float* __restrict__ B1, const float* __restrict__ B2,
    int ldb, float* __restrict__ part)
{
  constexpr int TX = BN/TN;
  constexpr int TY = BM/TM;
  static_assert(TX*TY==256, "256 threads");
  __shared__ float As[BK][BM+4];
  __shared__ float Bs[BK][BN+4];
  const int z = blockIdx.z;
  const float* A = A0 + (size_t)z*strideA;
  const float* B = (z==0)?B0:((z==1)?B1:B2);
  const int ks = blockIdx.x;
  const int tid = threadIdx.x;
  const int tx = tid % TX, ty = tid / TX;
  const int bm = blockIdx.y*BM;
  float acc[TM][TN];
  #pragma unroll
  for (int i=0;i<TM;i++)
    #pragma unroll
    for (int j=0;j<TN;j++) acc[i][j]=0.f;

  const int kbeg = ks*kch;
  for (int k0=kbeg; k0<kbeg+kch; k0+=BK){
    #pragma unroll
    for (int q=tid; q<BM*BK/4; q+=256){
      int m = q/(BK/4), kq = q - m*(BK/4);
      const float4 v = *(const float4*)&A[(size_t)(bm+m)*lda + k0 + kq*4];
      As[kq*4+0][m]=v.x; As[kq*4+1][m]=v.y; As[kq*4+2][m]=v.z; As[kq*4+3][m]=v.w;
    }
    if (WT){
      #pragma unroll
      for (int q=tid; q<BN*BK/4; q+=256){
        int nj = q/(BK/4), kq = q - nj*(BK/4);
        const float4 v = *(const float4*)&B[(size_t)nj*ldb + k0 + kq*4];
        Bs[kq*4+0][nj]=v.x; Bs[kq*4+1][nj]=v.y; Bs[kq*4+2][nj]=v.z; Bs[kq*4+3][nj]=v.w;
      }
    } else {
      #pragma unroll
      for (int q=tid; q<BN*BK/4; q+=256){
        int kk = q/(BN/4), nq = q - kk*(BN/4);
        const float4 v = *(const float4*)&B[(size_t)(k0+kk)*ldb + nq*4];
        *(float4*)&Bs[kk][nq*4] = v;
      }
    }
    __syncthreads();
    #pragma unroll
    for (int kk=0;kk<BK;kk++){
      float a[TM], b[TN];
      #pragma unroll
      for (int i=0;i<TM;i++) a[i]=As[kk][ty*TM+i];
      #pragma unroll
      for (int j=0;j<TN;j++) b[j]=Bs[kk][tx*TN+j];
      #pragma unroll
      for (int i=0;i<TM;i++)
        #pragma unroll
        for (int j=0;j<TN;j++) acc[i][j] = fmaf(a[i], b[j], acc[i][j]);
    }
    __syncthreads();
  }
  #pragma unroll
  for (int i=0;i<TM;i++){
    int row = bm+ty*TM+i;
    #pragma unroll
    for (int j4=0;j4<TN/4;j4++){
      float4 v = make_float4(acc[i][j4*4+0],acc[i][j4*4+1],acc[i][j4*4+2],acc[i][j4*4+3]);
      *(float4*)&part[(((size_t)(z*NKS+ks))*M + row)*BN + tx*TN + j4*4] = v;
    }
  }
}

// reduce hw2 partials -> nf columns [rel*128 .. rel*128+128) with leaky
__global__ __launch_bounds__(256) void k_hw2_red(const float* __restrict__ part,
                                                 float* __restrict__ nf){
  int t = blockIdx.x*256 + threadIdx.x;
  const int TOT = 3*NSEL*HID/4;
  if (t >= TOT) return;
  int rel = t / (NSEL*HID/4);
  int rem = t - rel*(NSEL*HID/4);
  int i = rem / (HID/4);
  int c4 = rem - i*(HID/4);
  float4 s = make_float4(0,0,0,0);
  #pragma unroll
  for (int ks=0; ks<KS3; ks++){
    const float4 v = *(const float4*)&part[(((size_t)(rel*KS3+ks))*NSEL + i)*HID + c4*4];
    s.x+=v.x; s.y+=v.y; s.z+=v.z; s.w+=v.w;
  }
  s.x=leaky1(s.x); s.y=leaky1(s.y); s.z=leaky1(s.z); s.w=leaky1(s.w);
  *(float4*)&nf[(size_t)i*FDIM + rel*HID + c4*4] = s;
}

// partial-reduce + bias + leaky + t3 projection, one wave per selected row
__global__ __launch_bounds__(256) void k_final_wave(
    const float* __restrict__ part, const float* __restrict__ t2b,
    const float* __restrict__ t3w, const float* __restrict__ t3b,
    float* __restrict__ outp)
{
  int w = (blockIdx.x*256 + threadIdx.x) >> 6;
  int j = threadIdx.x & 63;
  if (w >= NSEL) return;
  float v = 0.f;
  #pragma unroll
  for (int s=0;s<KS2;s++) v += part[((size_t)s*NSEL + w)*64 + j];
  v += t2b[j];
  v = leaky1(v);
  float a0 = v*t3w[j], a1 = v*t3w[64+j];
  #pragma unroll
  for (int sft=32;sft>0;sft>>=1){
    a0 += __shfl_down(a0,(unsigned)sft);
    a1 += __shfl_down(a1,(unsigned)sft);
  }
  if (j==0){
    outp[2*w+0] = a0 + t3b[0];
    outp[2*w+1] = a1 + t3b[1];
  }
}

// ---------- per-node gate scores ----------
template<int D>
__global__ __launch_bounds__(256) void k_scores(const float* __restrict__ X,
    const float* __restrict__ g0, const float* __restrict__ g1, const float* __restrict__ g2,
    float* __restrict__ sd, float* __restrict__ ss){
  int w = (blockIdx.x*256 + threadIdx.x) >> 6;
  int lane = threadIdx.x & 63;
  if (w >= NN) return;
  const float* x = X + (size_t)w*D;
  float a0=0,a1=0,a2=0,a3=0,a4=0,a5=0;
  for (int k=lane; k<D; k+=64){
    float v = x[k];
    a0 = fmaf(v, g0[k],   a0);  a1 = fmaf(v, g0[D+k], a1);
    a2 = fmaf(v, g1[k],   a2);  a3 = fmaf(v, g1[D+k], a3);
    a4 = fmaf(v, g2[k],   a4);  a5 = fmaf(v, g2[D+k], a5);
  }
  #pragma unroll
  for (int s=32;s>0;s>>=1){
    a0 += __shfl_down(a0,(unsigned)s); a1 += __shfl_down(a1,(unsigned)s);
    a2 += __shfl_down(a2,(unsigned)s); a3 += __shfl_down(a3,(unsigned)s);
    a4 += __shfl_down(a4,(unsigned)s); a5 += __shfl_down(a5,(unsigned)s);
  }
  if (lane==0){
    sd[0*NN+w]=a0; ss[0*NN+w]=a1;
    sd[1*NN+w]=a2; ss[1*NN+w]=a3;
    sd[2*NN+w]=a4; ss[2*NN+w]=a5;
  }
}

// ---------- aggregation with fused edge coefficients ----------
template<int D,int CH>
__global__ __launch_bounds__(D) void k_gather_f(const float* __restrict__ X,
    const int* __restrict__ off, const int* __restrict__ csrc,
    const float* __restrict__ sd, const float* __restrict__ ss,
    const float* __restrict__ dnv, const float* __restrict__ gb,
    float* __restrict__ outp){
  __shared__ float sc[CH];
  __shared__ int ssrc[CH];
  int n = blockIdx.x;
  int k = threadIdx.x;
  float sd_n = sd[n], dn_n = dnv[n], gbv = gb[0];
  float acc = EPSF * X[(size_t)n*D + k];
  int p0 = off[n], p1 = off[n+1];
  for (int pc=p0; pc<p1; pc+=CH){
    int m = min(CH, p1-pc);
    if (k < m){
      int s = csrc[pc+k];
      ssrc[k] = s;
      sc[k] = tanhf(sd_n + ss[s] + gbv) * dn_n * dnv[s];
    }
    __syncthreads();
    for (int j=0;j<m;j++){
      acc = fmaf(sc[j], X[(size_t)ssrc[j]*D + k], acc);
    }
    __syncthreads();
  }
  outp[(size_t)n*D + k] = acc;
}

template<int D,int CH>
__global__ __launch_bounds__(D) void k_gather_sel3(const float* __restrict__ X,
    const int* __restrict__ nodes,
    const int* __restrict__ off, const int* __restrict__ csrc,
    const float* __restrict__ sd, const float* __restrict__ ss,
    const float* __restrict__ dnv,
    const float* __restrict__ gb0, const float* __restrict__ gb1, const float* __restrict__ gb2,
    float* __restrict__ outp){
  __shared__ float sc[CH];
  __shared__ int ssrc[CH];
  int r = blockIdx.y;
  int i = blockIdx.x;
  int n = nodes[i];
  int k = threadIdx.x;
  const int* offr = off + r*(NN+1);
  const int* csr  = csrc + (size_t)r*NE;
  const float* sdr = sd + r*NN;
  const float* ssr = ss + r*NN;
  const float* dnr = dnv + r*NN;
  float gbv = ((r==0)?gb0:((r==1)?gb1:gb2))[0];
  float sd_n = sdr[n], dn_n = dnr[n];
  float acc = EPSF * X[(size_t)n*D + k];
  int p0 = offr[n], p1 = offr[n+1];
  for (int pc=p0; pc<p1; pc+=CH){
    int m = min(CH, p1-pc);
    if (k < m){
      int s = csr[pc+k];
      ssrc[k] = s;
      sc[k] = tanhf(sd_n + ssr[s] + gbv) * dn_n * dnr[s];
    }
    __syncthreads();
    for (int j=0;j<m;j++){
      acc = fmaf(sc[j], X[(size_t)ssrc[j]*D + k], acc);
    }
    __syncthreads();
  }
  outp[((size_t)r*NSEL + i)*D + k] = acc;
}

// ---------- gather raw0/raw1/raw2 rows into nf ----------
__global__ __launch_bounds__(192) void k_nf_fill(const float* __restrict__ h,
    const float* __restrict__ raw1, const float* __restrict__ raw2,
    const int* __restrict__ nodes, float* __restrict__ nf){
  int i = blockIdx.x;
  int n = nodes[i];
  for (int c=threadIdx.x; c<576; c+=192){
    float v; int col;
    if (c < 64)       { v = h[(size_t)n*IND + c];            col = 384 + c; }
    else if (c < 192) { int q=c-64;  v = raw1[(size_t)n*HID + q]; col = 448 + q; }
    else              { int q=c-192; v = raw2[(size_t)n*H3  + q]; col = 576 + q; }
    nf[(size_t)i*FDIM + col] = v;
  }
}

extern "C" void kernel_launch(void* const* d_in, const int* in_sizes, int n_in,
                              void* d_out, int out_size, void* d_ws, size_t ws_size,
                              hipStream_t stream){
  if (n_in < 32) return;
  const float* h = (const float*)d_in[0];
  const int* src[3] = {(const int*)d_in[1], (const int*)d_in[3], (const int*)d_in[5]};
  const int* dst[3] = {(const int*)d_in[2], (const int*)d_in[4], (const int*)d_in[6]};
  const int* nodes = (const int*)d_in[7];
  const float* t1w = (const float*)d_in[8];
  const float* t1b = (const float*)d_in[9];

  bool dictOrder = (in_sizes[12] == 768);
  const float *g1w[3],*g1b[3],*g2w[3],*g2b[3],*hw1[3],*hw2[3];
  for (int r=0;r<3;r++){
    if (dictOrder){
      int base = 10 + r*6;
      g1w[r]=(const float*)d_in[base+0]; g1b[r]=(const float*)d_in[base+1];
      g2w[r]=(const float*)d_in[base+2]; g2b[r]=(const float*)d_in[base+3];
      hw1[r]=(const float*)d_in[base+4]; hw2[r]=(const float*)d_in[base+5];
    } else {
      g1w[r]=(const float*)d_in[10+2*r]; g1b[r]=(const float*)d_in[11+2*r];
      g2w[r]=(const float*)d_in[16+2*r]; g2b[r]=(const float*)d_in[17+2*r];
      hw1[r]=(const float*)d_in[22+r];   hw2[r]=(const float*)d_in[25+r];
    }
  }
  const float* t2w = (const float*)d_in[28];
  const float* t2b = (const float*)d_in[29];
  const float* t3w = (const float*)d_in[30];
  const float* t3b = (const float*)d_in[31];
  float* outp = (float*)d_out;

  // workspace carve (~165.5 MB)
  char* w = (char*)d_ws;
  auto carve = [&](size_t elems)->void*{
    void* p = (void*)w;
    w += ((elems*4 + 255) & ~size_t(255));
    return p;
  };
  int*   deg  = (int*)  carve((size_t)6*NN);       // deg[3N] + cur[3N], one memset
  int*   cur  = deg + 3*NN;
  int*   off  = (int*)  carve((size_t)3*(NN+1));
  float* dnv  = (float*)carve((size_t)3*NN);
  int*   bsum = (int*)  carve((size_t)128);
  int*   csrc = (int*)  carve((size_t)3*NE);
  float* sd1  = (float*)carve((size_t)3*NN);
  float* ss1  = (float*)carve((size_t)3*NN);
  float* sd2  = (float*)carve((size_t)3*NN);
  float* ss2  = (float*)carve((size_t)3*NN);
  float* raw1 = (float*)carve((size_t)NN*HID);
  float* raw2 = (float*)carve((size_t)NN*H3);
  // union region (37.75 MB): pre1[NN*HID] | pre2[3*NSEL*H3]+hw2part[9*NSEL*HID] | t2part[KS2*NSEL*64]
  float* ureg = (float*)carve((size_t)3*NSEL*H3 + (size_t)3*KS3*NSEL*HID);
  float* pre1  = ureg;
  float* pre2  = ureg;
  float* hw2p  = ureg + (size_t)3*NSEL*H3;
  float* t2p   = ureg;
  float* nf   = (float*)carve((size_t)NSEL*FDIM);

  hipMemsetAsync(deg, 0, (size_t)6*NN*4, stream);
  k_deg   <<<(3*NE+255)/256, 256, 0, stream>>>(dst[0], dst[1], dst[2], deg);
  k_scan_a<<<3*NCHUNK, 256, 0, stream>>>(deg, off, bsum, dnv);
  k_scan_b<<<1, 64, 0, stream>>>(bsum);
  k_scan_c<<<3*NCHUNK, 256, 0, stream>>>(off, bsum);
  k_fill2 <<<(3*NE+255)/256, 256, 0, stream>>>(src[0],dst[0],src[1],dst[1],src[2],dst[2],
                                               off, cur, csrc);

  // raw1 = leaky(h @ t1_w^T + t1_b)
  k_gemm<64,128,32,4,8,true,true><<<dim3(1,(NN+63)/64), 256, 0, stream>>>(
      h, IND, NN, IND, t1w, IND, t1b, raw1, HID);

  k_scores<HID><<<(NN+3)/4, 256, 0, stream>>>(raw1, g1w[0], g1w[1], g1w[2], sd1, ss1);

  for (int r=0;r<3;r++){
    k_gather_f<HID,128><<<NN, HID, 0, stream>>>(raw1, off+r*(NN+1), csrc+(size_t)r*NE,
                                                sd1+r*NN, ss1+r*NN, dnv+r*NN, g1b[r], pre1);
    k_gemm<64,128,32,4,8,false,false><<<dim3(1,(NN+63)/64), 256, 0, stream>>>(
        pre1, HID, NN, HID, hw1[r], HID, nullptr, raw2 + r*HID, H3);
  }

  k_scores<H3><<<(NN+3)/4, 256, 0, stream>>>(raw2, g2w[0], g2w[1], g2w[2], sd2, ss2);

  // batched selected gather over 3 relations
  k_gather_sel3<H3,128><<<dim3(NSEL,3), H3, 0, stream>>>(raw2, nodes, off, csrc,
      sd2, ss2, dnv, g2b[0], g2b[1], g2b[2], pre2);

  // hw2: split-K x3, z-batched over relations -> partials -> reduce into nf
  k_sk<32,128,32,2,8,false,KS3><<<dim3(KS3, NSEL/32, 3), 256, 0, stream>>>(
      pre2, H3, NSEL, KCH3, (size_t)NSEL*H3, hw2[0], hw2[1], hw2[2], HID, hw2p);
  k_hw2_red<<<(3*NSEL*HID/4 + 255)/256, 256, 0, stream>>>(hw2p, nf);

  k_nf_fill<<<NSEL, 192, 0, stream>>>(h, raw1, raw2, nodes, nf);

  // t2 split-K x10 partials then fused reduce + leaky + t3
  k_sk<64,64,32,4,4,true,1><<<dim3(KS2, NSEL/64, 1), 256, 0, stream>>>(
      nf, FDIM, NSEL, KCH2, 0, t2w, t2w, t2w, FDIM, t2p);
  k_final_wave<<<(NSEL*64+255)/256, 256, 0, stream>>>(t2p, t2b, t3w, t3b, outp);
}